// Round 5
// baseline (349.415 us; speedup 1.0000x reference)
//
#include <hip/hip_runtime.h>

typedef short short8 __attribute__((ext_vector_type(8)));
typedef float f32x4 __attribute__((ext_vector_type(4)));

#define NEG 0.01f

static __device__ __forceinline__ float leaky(float x) { return x >= 0.f ? x : NEG * x; }

static __device__ __forceinline__ unsigned short f2bf(float f) {
    unsigned int u = __float_as_uint(f);
    unsigned int r = (u + 0x7fff + ((u >> 16) & 1)) >> 16;
    return (unsigned short)r;
}

// ---------------- 1. maxpool 2x2 (both tensors), NCHW fp32 ----------------
__global__ __launch_bounds__(256) void pool_kernel(const float* __restrict__ rgb,
                                                   const float* __restrict__ ir,
                                                   float* __restrict__ Pr,
                                                   float* __restrict__ Pi) {
    const float* src = blockIdx.y ? ir : rgb;
    float* dst = blockIdx.y ? Pi : Pr;
    int q = blockIdx.x * 256 + threadIdx.x;   // float4 index, 524288 total
    int ow4 = q & 15;                          // 16 float4 per out row
    int t = q >> 4;
    int oh = t & 63;
    int nc = t >> 6;                           // n*128+c
    const float* ib = src + ((size_t)(nc * 128 + 2 * oh)) * 128 + ow4 * 8;
    float4 a0 = *(const float4*)(ib);
    float4 a1 = *(const float4*)(ib + 4);
    float4 b0 = *(const float4*)(ib + 128);
    float4 b1 = *(const float4*)(ib + 132);
    float4 o;
    o.x = fmaxf(fmaxf(a0.x, a0.y), fmaxf(b0.x, b0.y));
    o.y = fmaxf(fmaxf(a0.z, a0.w), fmaxf(b0.z, b0.w));
    o.z = fmaxf(fmaxf(a1.x, a1.y), fmaxf(b1.x, b1.y));
    o.w = fmaxf(fmaxf(a1.z, a1.w), fmaxf(b1.z, b1.w));
    *(float4*)(dst + (size_t)q * 4) = o;
}

// ---- 2. transpose to (n,hw,c), l2-normalize -> bf16; batch0 fp32 rows ----
__global__ __launch_bounds__(256) void normT_kernel(const float* __restrict__ Pr,
                                                    const float* __restrict__ Pi,
                                                    float* __restrict__ Pt0r,
                                                    float* __restrict__ Pt0i,
                                                    unsigned short* __restrict__ xnr,
                                                    unsigned short* __restrict__ xni) {
    const float* P = blockIdx.z ? Pi : Pr;
    float* Pt0 = blockIdx.z ? Pt0i : Pt0r;
    unsigned short* xn = blockIdx.z ? xni : xnr;
    int n = blockIdx.y;
    int hw0 = blockIdx.x * 32;
    __shared__ float tile[32][129];
    __shared__ float psum[32][8];
    __shared__ float invn[32];
    int hwl = threadIdx.x & 31;
    int cg = threadIdx.x >> 5;
    float ssq = 0.f;
#pragma unroll
    for (int ii = 0; ii < 16; ++ii) {
        int c = cg * 16 + ii;
        float v = P[((size_t)(n * 128 + c)) * 4096 + hw0 + hwl];
        tile[hwl][c] = v;
        ssq += v * v;
    }
    psum[hwl][cg] = ssq;
    __syncthreads();
    if (threadIdx.x < 32) {
        float s = 0.f;
#pragma unroll
        for (int g = 0; g < 8; ++g) s += psum[threadIdx.x][g];
        invn[threadIdx.x] = 1.0f / fmaxf(sqrtf(s), 1e-12f);
    }
    __syncthreads();
    int c = threadIdx.x & 127;
    int rh = threadIdx.x >> 7;
#pragma unroll
    for (int rr = 0; rr < 16; ++rr) {
        int r = rh * 16 + rr;
        float v = tile[r][c];
        xn[((size_t)n * 4096 + hw0 + r) * 128 + c] = f2bf(v * invn[r]);
        if (n == 0) Pt0[(size_t)(hw0 + r) * 128 + c] = v;
    }
}

// ------ 3. fused gram (bf16 MFMA, A direct from L2) + sorted top-16 -------
// grid: (128 row-blocks of 32 queries, 4 batches, 2 modalities); 128 thr.
// No LDS staging, no in-loop barriers: lane (frow,kg)'s A-fragment for MFMA
// (ar,kt) is the contiguous 16B global slice row=t*64+ar*16+frow,
// bytes kt*64+kg*16 -> wave access = 16 rows x 64B, fully coalesced,
// L2-resident (8 x 1MB tables). acc init = 2.0 biases scores positive so
// raw float bits are order-monotone; packed (bits|idx), Batcher sort-16 +
// bitonic merge into sorted running top-16 -> branch-free, no divergence.
__global__ __launch_bounds__(128, 4) void knn_kernel(const unsigned short* __restrict__ xnr,
                                                     const unsigned short* __restrict__ xni,
                                                     int* __restrict__ knnr,
                                                     int* __restrict__ knni) {
    __shared__ unsigned mbuf[32 * 65];
    const int n = blockIdx.y;
    const unsigned short* xn = blockIdx.z ? xni : xnr;
    int* knn = blockIdx.z ? knni : knnr;
    const int r0 = blockIdx.x * 32;
    const int tid = threadIdx.x;
    const int wave = tid >> 6, lane = tid & 63;
    const int frow = lane & 15, kg = lane >> 4;
    const int kg16 = kg * 16;

    // B-fragments: this wave's 16 query rows, loaded once
    short8 bq[4];
    {
        const unsigned short* qsrc = xn + ((size_t)n * 4096 + r0 + wave * 16 + frow) * 128;
#pragma unroll
        for (int kt = 0; kt < 4; ++kt)
            bq[kt] = *(const short8*)(qsrc + kt * 32 + kg * 8);
    }

    // per-lane A base: row frow, k-slice kg*8
    const unsigned short* abase = xn + (size_t)n * 4096 * 128 + frow * 128 + kg * 8;

    unsigned val[16];   // running top-16, sorted descending
#pragma unroll
    for (int s = 0; s < 16; ++s) val[s] = 0u;

    for (int t = 0; t < 64; ++t) {
        const unsigned short* pt = abase + (size_t)t * 64 * 128;
        f32x4 acc0 = {2.f, 2.f, 2.f, 2.f}, acc1 = {2.f, 2.f, 2.f, 2.f};
        f32x4 acc2 = {2.f, 2.f, 2.f, 2.f}, acc3 = {2.f, 2.f, 2.f, 2.f};
#define ARG(AR, ACC)                                                        \
    {                                                                       \
        short8 a0 = *(const short8*)(pt + AR * 16 * 128);                   \
        short8 a1 = *(const short8*)(pt + AR * 16 * 128 + 32);              \
        short8 a2 = *(const short8*)(pt + AR * 16 * 128 + 64);              \
        short8 a3 = *(const short8*)(pt + AR * 16 * 128 + 96);              \
        ACC = __builtin_amdgcn_mfma_f32_16x16x32_bf16(a0, bq[0], ACC, 0, 0, 0); \
        ACC = __builtin_amdgcn_mfma_f32_16x16x32_bf16(a1, bq[1], ACC, 0, 0, 0); \
        ACC = __builtin_amdgcn_mfma_f32_16x16x32_bf16(a2, bq[2], ACC, 0, 0, 0); \
        ACC = __builtin_amdgcn_mfma_f32_16x16x32_bf16(a3, bq[3], ACC, 0, 0, 0); \
    }
        ARG(0, acc0) ARG(1, acc1) ARG(2, acc2) ARG(3, acc3)
#undef ARG

        // pack: positive-biased score bits (top 20) | candidate idx (12 bits)
        unsigned pk[16];
        const int cb = t * 64 + kg * 4;
#define PACK(AC, A_)                                                                        \
    {                                                                                       \
        _Pragma("unroll") for (int j = 0; j < 4; ++j) {                                     \
            pk[A_ * 4 + j] = (__float_as_uint(AC[j]) & 0xFFFFF000u) |                       \
                             (unsigned)(cb + A_ * 16 + j);                                  \
        }                                                                                   \
    }
        PACK(acc0, 0) PACK(acc1, 1) PACK(acc2, 2) PACK(acc3, 3)
#undef PACK

        // Batcher odd-even mergesort, 16 elements, descending (63 CE)
#define CE(i, j)                                          \
    {                                                     \
        unsigned mx = max(pk[i], pk[j]);                  \
        unsigned mn = min(pk[i], pk[j]);                  \
        pk[i] = mx; pk[j] = mn;                           \
    }
        CE(0,1) CE(2,3) CE(4,5) CE(6,7) CE(8,9) CE(10,11) CE(12,13) CE(14,15)
        CE(0,2) CE(1,3) CE(4,6) CE(5,7) CE(8,10) CE(9,11) CE(12,14) CE(13,15)
        CE(1,2) CE(5,6) CE(9,10) CE(13,14)
        CE(0,4) CE(1,5) CE(2,6) CE(3,7) CE(8,12) CE(9,13) CE(10,14) CE(11,15)
        CE(2,4) CE(3,5) CE(10,12) CE(11,13)
        CE(1,2) CE(3,4) CE(5,6) CE(9,10) CE(11,12) CE(13,14)
        CE(0,8) CE(1,9) CE(2,10) CE(3,11) CE(4,12) CE(5,13) CE(6,14) CE(7,15)
        CE(4,8) CE(5,9) CE(6,10) CE(7,11)
        CE(2,4) CE(3,5) CE(6,8) CE(7,9) CE(10,12) CE(11,13)
        CE(1,2) CE(3,4) CE(5,6) CE(7,8) CE(9,10) CE(11,12) CE(13,14)
#undef CE

        // half-cleaner: top-16 of merge(val desc, pk desc) as bitonic seq
#pragma unroll
        for (int i = 0; i < 16; ++i) val[i] = max(val[i], pk[15 - i]);
        // bitonic merge -> descending sorted
#define CEV(i, j)                                         \
    {                                                     \
        unsigned mx = max(val[i], val[j]);                \
        unsigned mn = min(val[i], val[j]);                \
        val[i] = mx; val[j] = mn;                         \
    }
        CEV(0,8) CEV(1,9) CEV(2,10) CEV(3,11) CEV(4,12) CEV(5,13) CEV(6,14) CEV(7,15)
        CEV(0,4) CEV(1,5) CEV(2,6) CEV(3,7) CEV(8,12) CEV(9,13) CEV(10,14) CEV(11,15)
        CEV(0,2) CEV(1,3) CEV(4,6) CEV(5,7) CEV(8,10) CEV(9,11) CEV(12,14) CEV(13,15)
        CEV(0,1) CEV(2,3) CEV(4,5) CEV(6,7) CEV(8,9) CEV(10,11) CEV(12,13) CEV(14,15)
#undef CEV
    }

    // final: 4 sorted runs of 16 per query -> 4-way merge, top-16 out
    {
        int query = wave * 16 + frow;
#pragma unroll
        for (int s = 0; s < 16; ++s) mbuf[query * 65 + kg16 + s] = val[s];
        if (tid < 32) mbuf[tid * 65 + 64] = 0;
        __syncthreads();
        if (tid < 32) {
            int* outp = knn + ((size_t)n * 4096 + r0 + tid) * 16;
            const unsigned* row = mbuf + tid * 65;
            int h0 = 0, h1 = 0, h2 = 0, h3 = 0;
#pragma unroll 1
            for (int kk = 0; kk < 16; ++kk) {
                unsigned c0 = row[h0], c1 = row[16 + h1], c2 = row[32 + h2], c3 = row[48 + h3];
                unsigned mm = max(max(c0, c1), max(c2, c3));
                outp[kk] = (int)(mm & 0xFFFu);
                h0 += (c0 == mm); h1 += (c1 == mm); h2 += (c2 == mm); h3 += (c3 == mm);
            }
        }
    }
}

// --- 4. node tables: A1=hr@(W1+W2), A2=hi@W2, B1=hi@(V1+V2), B2=hr@V2 -----
__global__ __launch_bounds__(256) void table_kernel(const float* __restrict__ Pt0r,
                                                    const float* __restrict__ Pt0i,
                                                    const float* __restrict__ Wr,
                                                    const float* __restrict__ Wi,
                                                    float* __restrict__ A1, float* __restrict__ A2,
                                                    float* __restrict__ B1, float* __restrict__ B2) {
    int tbl = blockIdx.y;
    const float* X = (tbl == 0 || tbl == 3) ? Pt0r : Pt0i;
    const float* W = (tbl <= 1) ? Wr : Wi;
    bool comb = (tbl == 0 || tbl == 2);
    float* out = tbl == 0 ? A1 : tbl == 1 ? A2 : tbl == 2 ? B1 : B2;
    __shared__ float Xl[32][128];
    int j0 = blockIdx.x * 32;
    for (int q = threadIdx.x; q < 32 * 128; q += 256)
        Xl[q >> 7][q & 127] = X[(size_t)(j0 + (q >> 7)) * 128 + (q & 127)];
    __syncthreads();
    int c = threadIdx.x & 127;
    int jh = threadIdx.x >> 7;
    float acc[16];
#pragma unroll
    for (int s = 0; s < 16; ++s) acc[s] = 0.f;
    for (int d4 = 0; d4 < 32; ++d4) {
        float w[4];
#pragma unroll
        for (int u = 0; u < 4; ++u) {
            int d = d4 * 4 + u;
            w[u] = W[(size_t)(d + 128) * 128 + c];
            if (comb) w[u] += W[(size_t)d * 128 + c];
        }
#pragma unroll
        for (int jj = 0; jj < 16; ++jj) {
            const float4 xv = *(const float4*)&Xl[jh * 16 + jj][d4 * 4];
            acc[jj] = fmaf(xv.x, w[0], fmaf(xv.y, w[1], fmaf(xv.z, w[2], fmaf(xv.w, w[3], acc[jj]))));
        }
    }
#pragma unroll
    for (int jj = 0; jj < 16; ++jj)
        out[(size_t)(j0 + jh * 16 + jj) * 128 + c] = acc[jj];
}

// ------ 5. pair accumulation: sum leaky(A1[a]-A2[b]+br), per batch --------
__global__ __launch_bounds__(256) void pairsum_kernel(const int* __restrict__ knnr,
                                                      const int* __restrict__ knni,
                                                      const float* __restrict__ A1,
                                                      const float* __restrict__ A2,
                                                      const float* __restrict__ B1,
                                                      const float* __restrict__ B2,
                                                      const float* __restrict__ b_rgb,
                                                      const float* __restrict__ b_ir,
                                                      float* __restrict__ Spart) {
    __shared__ int ia[512], ib[512];
    int chunk = blockIdx.x, n = blockIdx.y;
    int i0 = chunk * 32;
    for (int q = threadIdx.x; q < 512; q += 256) {
        int i = i0 + (q >> 4), kk = q & 15;
        ia[q] = knnr[((size_t)n * 4096 + i) * 16 + kk];
        ib[q] = knni[((size_t)n * 4096 + i) * 16 + kk];
    }
    __syncthreads();
    int c = threadIdx.x & 127, ph = threadIdx.x >> 7;
    float br = b_rgb[c], bi = b_ir[c];
    float accR = 0.f, accI = 0.f;
#pragma unroll 8
    for (int q = ph; q < 512; q += 2) {
        int a = ia[q], b = ib[q];
        float a1 = A1[(size_t)a * 128 + c];
        float a2 = A2[(size_t)b * 128 + c];
        float b1 = B1[(size_t)b * 128 + c];
        float b2 = B2[(size_t)a * 128 + c];
        accR += leaky(a1 - a2 + br);
        accI += leaky(b1 - b2 + bi);
    }
    size_t o = (((size_t)n * 128 + chunk) * 2 + ph) * 256;
    Spart[o + c] = accR;
    Spart[o + 128 + c] = accI;
}

// ---------- 6a. partial reduce of Spart: 256 partials -> 16 ----------------
__global__ __launch_bounds__(256) void reduce_kernel(const float* __restrict__ Spart,
                                                     float* __restrict__ Spart2) {
    int seg = blockIdx.x, n = blockIdx.y;
    int d = threadIdx.x;
    float s = 0.f;
#pragma unroll
    for (int j = 0; j < 16; ++j)
        s += Spart[((size_t)n * 256 + seg * 16 + j) * 256 + d];
    Spart2[((size_t)n * 16 + seg) * 256 + d] = s;
}

// --------------------- 6b. SE gate (tiny, 1 block/batch) ------------------
__global__ __launch_bounds__(256) void gate_kernel(const float* __restrict__ Spart2,
                                                   const float* __restrict__ se_w1,
                                                   const float* __restrict__ se_b1,
                                                   const float* __restrict__ se_w2,
                                                   const float* __restrict__ se_b2,
                                                   float* __restrict__ gate) {
    int n = blockIdx.x;
    __shared__ float m[256];
    __shared__ float hid[8];
    int d = threadIdx.x;
    float s = 0.f;
#pragma unroll
    for (int seg = 0; seg < 16; ++seg)
        s += Spart2[((size_t)n * 16 + seg) * 256 + d];
    m[d] = s * (1.0f / 65536.0f);
    __syncthreads();
    if (threadIdx.x < 8) {
        float h = se_b1[threadIdx.x];
        for (int dd = 0; dd < 256; ++dd) h += m[dd] * se_w1[dd * 8 + threadIdx.x];
        hid[threadIdx.x] = leaky(h);
    }
    __syncthreads();
    if (threadIdx.x < 128) {
        float z = se_b2[threadIdx.x];
#pragma unroll
        for (int j = 0; j < 8; ++j) z += hid[j] * se_w2[j * 128 + threadIdx.x];
        gate[n * 128 + threadIdx.x] = 1.0f / (1.0f + expf(-z));
    }
}

// -------------------- 7. blend + relu, NCHW output ------------------------
__global__ __launch_bounds__(256) void out_kernel(const float* __restrict__ Pr,
                                                  const float* __restrict__ Pi,
                                                  const float* __restrict__ gate,
                                                  const float* __restrict__ g1p,
                                                  const float* __restrict__ g2p,
                                                  float* __restrict__ out) {
    int q = blockIdx.x * 256 + threadIdx.x;  // float4 idx, 524288 total
    int nc = q >> 10;
    float g = gate[nc];
    float gr = g1p[0] * g, gi = g2p[0] * (1.f - g);
    float4 r = *(const float4*)(Pr + (size_t)q * 4);
    float4 i = *(const float4*)(Pi + (size_t)q * 4);
    float4 o;
    o.x = fmaxf(gr * r.x + gi * i.x, 0.f);
    o.y = fmaxf(gr * r.y + gi * i.y, 0.f);
    o.z = fmaxf(gr * r.z + gi * i.z, 0.f);
    o.w = fmaxf(gr * r.w + gi * i.w, 0.f);
    *(float4*)(out + (size_t)q * 4) = o;
}

extern "C" void kernel_launch(void* const* d_in, const int* in_sizes, int n_in,
                              void* d_out, int out_size, void* d_ws, size_t ws_size,
                              hipStream_t stream) {
    const float* rgb = (const float*)d_in[0];
    const float* ir = (const float*)d_in[1];
    const float* Wr = (const float*)d_in[2];
    const float* br = (const float*)d_in[3];
    const float* Wi = (const float*)d_in[4];
    const float* bi = (const float*)d_in[5];
    const float* sw1 = (const float*)d_in[6];
    const float* sb1 = (const float*)d_in[7];
    const float* sw2 = (const float*)d_in[8];
    const float* sb2 = (const float*)d_in[9];
    const float* g1 = (const float*)d_in[10];
    const float* g2 = (const float*)d_in[11];
    float* out = (float*)d_out;

    char* ws = (char*)d_ws;
    float* Pr = (float*)ws;                     ws += (size_t)8 << 20;
    float* Pi = (float*)ws;                     ws += (size_t)8 << 20;
    unsigned short* xnr = (unsigned short*)ws;  ws += (size_t)4 << 20;
    unsigned short* xni = (unsigned short*)ws;  ws += (size_t)4 << 20;
    float* Pt0r = (float*)ws;                   ws += (size_t)2 << 20;
    float* Pt0i = (float*)ws;                   ws += (size_t)2 << 20;
    int* knnr = (int*)ws;                       ws += (size_t)1 << 20;
    int* knni = (int*)ws;                       ws += (size_t)1 << 20;
    float* A1 = (float*)ws;                     ws += (size_t)2 << 20;
    float* A2 = (float*)ws;                     ws += (size_t)2 << 20;
    float* B1 = (float*)ws;                     ws += (size_t)2 << 20;
    float* B2 = (float*)ws;                     ws += (size_t)2 << 20;
    float* Spart = (float*)ws;                  ws += (size_t)1 << 20;
    float* Spart2 = (float*)ws;                 ws += (size_t)64 << 10;
    float* gate = (float*)ws;                   ws += 4096;

    pool_kernel<<<dim3(2048, 2), 256, 0, stream>>>(rgb, ir, Pr, Pi);
    normT_kernel<<<dim3(128, 4, 2), 256, 0, stream>>>(Pr, Pi, Pt0r, Pt0i, xnr, xni);
    knn_kernel<<<dim3(128, 4, 2), 128, 0, stream>>>(xnr, xni, knnr, knni);
    table_kernel<<<dim3(128, 4), 256, 0, stream>>>(Pt0r, Pt0i, Wr, Wi, A1, A2, B1, B2);
    pairsum_kernel<<<dim3(128, 4), 256, 0, stream>>>(knnr, knni, A1, A2, B1, B2, br, bi, Spart);
    reduce_kernel<<<dim3(16, 4), 256, 0, stream>>>(Spart, Spart2);
    gate_kernel<<<4, 256, 0, stream>>>(Spart2, sw1, sb1, sw2, sb2, gate);
    out_kernel<<<2048, 256, 0, stream>>>(Pr, Pi, gate, g1, g2, out);
}

// Round 6
// 208.807 us; speedup vs baseline: 1.6734x; 1.6734x over previous
//
#include <hip/hip_runtime.h>

typedef short short8 __attribute__((ext_vector_type(8)));
typedef float f32x4 __attribute__((ext_vector_type(4)));

#define NEG 0.01f

static __device__ __forceinline__ float leaky(float x) { return x >= 0.f ? x : NEG * x; }

static __device__ __forceinline__ unsigned short f2bf(float f) {
    unsigned int u = __float_as_uint(f);
    unsigned int r = (u + 0x7fff + ((u >> 16) & 1)) >> 16;
    return (unsigned short)r;
}

// ---------------- 1. maxpool 2x2 (both tensors), NCHW fp32 ----------------
__global__ __launch_bounds__(256) void pool_kernel(const float* __restrict__ rgb,
                                                   const float* __restrict__ ir,
                                                   float* __restrict__ Pr,
                                                   float* __restrict__ Pi) {
    const float* src = blockIdx.y ? ir : rgb;
    float* dst = blockIdx.y ? Pi : Pr;
    int q = blockIdx.x * 256 + threadIdx.x;   // float4 index, 524288 total
    int ow4 = q & 15;                          // 16 float4 per out row
    int t = q >> 4;
    int oh = t & 63;
    int nc = t >> 6;                           // n*128+c
    const float* ib = src + ((size_t)(nc * 128 + 2 * oh)) * 128 + ow4 * 8;
    float4 a0 = *(const float4*)(ib);
    float4 a1 = *(const float4*)(ib + 4);
    float4 b0 = *(const float4*)(ib + 128);
    float4 b1 = *(const float4*)(ib + 132);
    float4 o;
    o.x = fmaxf(fmaxf(a0.x, a0.y), fmaxf(b0.x, b0.y));
    o.y = fmaxf(fmaxf(a0.z, a0.w), fmaxf(b0.z, b0.w));
    o.z = fmaxf(fmaxf(a1.x, a1.y), fmaxf(b1.x, b1.y));
    o.w = fmaxf(fmaxf(a1.z, a1.w), fmaxf(b1.z, b1.w));
    *(float4*)(dst + (size_t)q * 4) = o;
}

// ---- 2. transpose to (n,hw,c), l2-normalize -> bf16; batch0 fp32 rows ----
__global__ __launch_bounds__(256) void normT_kernel(const float* __restrict__ Pr,
                                                    const float* __restrict__ Pi,
                                                    float* __restrict__ Pt0r,
                                                    float* __restrict__ Pt0i,
                                                    unsigned short* __restrict__ xnr,
                                                    unsigned short* __restrict__ xni) {
    const float* P = blockIdx.z ? Pi : Pr;
    float* Pt0 = blockIdx.z ? Pt0i : Pt0r;
    unsigned short* xn = blockIdx.z ? xni : xnr;
    int n = blockIdx.y;
    int hw0 = blockIdx.x * 32;
    __shared__ float tile[32][129];
    __shared__ float psum[32][8];
    __shared__ float invn[32];
    int hwl = threadIdx.x & 31;
    int cg = threadIdx.x >> 5;
    float ssq = 0.f;
#pragma unroll
    for (int ii = 0; ii < 16; ++ii) {
        int c = cg * 16 + ii;
        float v = P[((size_t)(n * 128 + c)) * 4096 + hw0 + hwl];
        tile[hwl][c] = v;
        ssq += v * v;
    }
    psum[hwl][cg] = ssq;
    __syncthreads();
    if (threadIdx.x < 32) {
        float s = 0.f;
#pragma unroll
        for (int g = 0; g < 8; ++g) s += psum[threadIdx.x][g];
        invn[threadIdx.x] = 1.0f / fmaxf(sqrtf(s), 1e-12f);
    }
    __syncthreads();
    int c = threadIdx.x & 127;
    int rh = threadIdx.x >> 7;
#pragma unroll
    for (int rr = 0; rr < 16; ++rr) {
        int r = rh * 16 + rr;
        float v = tile[r][c];
        xn[((size_t)n * 4096 + hw0 + r) * 128 + c] = f2bf(v * invn[r]);
        if (n == 0) Pt0[(size_t)(hw0 + r) * 128 + c] = v;
    }
}

// ------ 3. fused gram (bf16 MFMA) + sorted top-16, candidate-split --------
// grid: (64 row-blocks of 64 queries, 2 cand-halves, 8 nz); 256 thr (4 waves).
// LDS dbuf staging + register prefetch (R4 pipeline), candidate axis split in
// halves for 2x occupancy (16 waves/CU). Per lane: 16 scores/tile packed
// (positive-biased float bits | 12-bit idx), Batcher sort-16 + bitonic merge
// into sorted running top-16; per-query 4 kg-runs merged in-kernel; sorted
// packed top-16 per (query,half) written for cross-half merge kernel.
__global__ __launch_bounds__(256) void knn_kernel(const unsigned short* __restrict__ xnr,
                                                  const unsigned short* __restrict__ xni,
                                                  unsigned* __restrict__ Cand) {
    __shared__ __align__(16) char smem[32768];   // 2 x 16KB candidate tiles
    const int nz = blockIdx.z;
    const int n = nz >> 1;
    const unsigned short* xn = (nz & 1) ? xni : xnr;
    const int half = blockIdx.y;
    const int r0 = blockIdx.x * 64;
    const int tid = threadIdx.x;
    const int wave = tid >> 6, lane = tid & 63;
    const int frow = lane & 15, kg = lane >> 4;
    const int aswz = (frow & 7) << 4;
    const int kg16 = kg * 16;
    const int cand0 = half * 2048;

    // B-fragments: this wave's 16 query rows, loaded once
    short8 bq[4];
    {
        const unsigned short* qsrc = xn + ((size_t)n * 4096 + r0 + wave * 16 + frow) * 128;
#pragma unroll
        for (int kt = 0; kt < 4; ++kt)
            bq[kt] = *(const short8*)(qsrc + kt * 32 + kg * 8);
    }

    // stage tile 0 into buf0 (XOR-swizzled rows of 256B)
    {
        const unsigned short* src = xn + ((size_t)n * 4096 + cand0) * 128;
#pragma unroll
        for (int it = 0; it < 4; ++it) {
            int idx = it * 256 + tid;
            int r = idx >> 4, ch = idx & 15;
            short8 v = *(const short8*)(src + r * 128 + ch * 8);
            *(short8*)(smem + r * 256 + ((ch * 16) ^ ((r & 7) << 4))) = v;
        }
    }
    __syncthreads();

    unsigned val[16];   // running top-16, sorted descending
#pragma unroll
    for (int s = 0; s < 16; ++s) val[s] = 0u;

    for (int t = 0; t < 32; ++t) {
        // prefetch next candidate tile into regs
        short8 g[4];
        if (t < 31) {
            const unsigned short* src = xn + ((size_t)n * 4096 + cand0 + (t + 1) * 64) * 128;
#pragma unroll
            for (int it = 0; it < 4; ++it) {
                int idx = it * 256 + tid;
                g[it] = *(const short8*)(src + (idx >> 4) * 128 + (idx & 15) * 8);
            }
        }
        const char* bc = smem + ((t & 1) ? 16384 : 0);
        f32x4 acc0 = {2.f, 2.f, 2.f, 2.f}, acc1 = {2.f, 2.f, 2.f, 2.f};
        f32x4 acc2 = {2.f, 2.f, 2.f, 2.f}, acc3 = {2.f, 2.f, 2.f, 2.f};
#pragma unroll
        for (int kt = 0; kt < 4; ++kt) {
            int ko = (kt * 64 + kg16) ^ aswz;
            short8 b = bq[kt];
            short8 a0 = *(const short8*)(bc + (frow)*256 + ko);
            short8 a1 = *(const short8*)(bc + (16 + frow) * 256 + ko);
            short8 a2 = *(const short8*)(bc + (32 + frow) * 256 + ko);
            short8 a3 = *(const short8*)(bc + (48 + frow) * 256 + ko);
            acc0 = __builtin_amdgcn_mfma_f32_16x16x32_bf16(a0, b, acc0, 0, 0, 0);
            acc1 = __builtin_amdgcn_mfma_f32_16x16x32_bf16(a1, b, acc1, 0, 0, 0);
            acc2 = __builtin_amdgcn_mfma_f32_16x16x32_bf16(a2, b, acc2, 0, 0, 0);
            acc3 = __builtin_amdgcn_mfma_f32_16x16x32_bf16(a3, b, acc3, 0, 0, 0);
        }
        // pack: positive-biased score bits (top 20) | candidate idx (12 bits)
        unsigned pk[16];
        const int cb = cand0 + t * 64 + kg * 4;
#define PACK(AC, A_)                                                                        \
    {                                                                                       \
        _Pragma("unroll") for (int j = 0; j < 4; ++j) {                                     \
            pk[A_ * 4 + j] = (__float_as_uint(AC[j]) & 0xFFFFF000u) |                       \
                             (unsigned)(cb + A_ * 16 + j);                                  \
        }                                                                                   \
    }
        PACK(acc0, 0) PACK(acc1, 1) PACK(acc2, 2) PACK(acc3, 3)
#undef PACK

        // Batcher odd-even mergesort, 16 elements, descending (63 CE)
#define CE(i, j)                                          \
    {                                                     \
        unsigned mx = max(pk[i], pk[j]);                  \
        unsigned mn = min(pk[i], pk[j]);                  \
        pk[i] = mx; pk[j] = mn;                           \
    }
        CE(0,1) CE(2,3) CE(4,5) CE(6,7) CE(8,9) CE(10,11) CE(12,13) CE(14,15)
        CE(0,2) CE(1,3) CE(4,6) CE(5,7) CE(8,10) CE(9,11) CE(12,14) CE(13,15)
        CE(1,2) CE(5,6) CE(9,10) CE(13,14)
        CE(0,4) CE(1,5) CE(2,6) CE(3,7) CE(8,12) CE(9,13) CE(10,14) CE(11,15)
        CE(2,4) CE(3,5) CE(10,12) CE(11,13)
        CE(1,2) CE(3,4) CE(5,6) CE(9,10) CE(11,12) CE(13,14)
        CE(0,8) CE(1,9) CE(2,10) CE(3,11) CE(4,12) CE(5,13) CE(6,14) CE(7,15)
        CE(4,8) CE(5,9) CE(6,10) CE(7,11)
        CE(2,4) CE(3,5) CE(6,8) CE(7,9) CE(10,12) CE(11,13)
        CE(1,2) CE(3,4) CE(5,6) CE(7,8) CE(9,10) CE(11,12) CE(13,14)
#undef CE

        // half-cleaner: top-16 of merge(val desc, pk desc) as bitonic seq
#pragma unroll
        for (int i = 0; i < 16; ++i) val[i] = max(val[i], pk[15 - i]);
        // bitonic merge -> descending sorted
#define CEV(i, j)                                         \
    {                                                     \
        unsigned mx = max(val[i], val[j]);                \
        unsigned mn = min(val[i], val[j]);                \
        val[i] = mx; val[j] = mn;                         \
    }
        CEV(0,8) CEV(1,9) CEV(2,10) CEV(3,11) CEV(4,12) CEV(5,13) CEV(6,14) CEV(7,15)
        CEV(0,4) CEV(1,5) CEV(2,6) CEV(3,7) CEV(8,12) CEV(9,13) CEV(10,14) CEV(11,15)
        CEV(0,2) CEV(1,3) CEV(4,6) CEV(5,7) CEV(8,10) CEV(9,11) CEV(12,14) CEV(13,15)
        CEV(0,1) CEV(2,3) CEV(4,5) CEV(6,7) CEV(8,9) CEV(10,11) CEV(12,13) CEV(14,15)
#undef CEV

        if (t < 31) {
            char* bn = smem + ((t & 1) ? 0 : 16384);
#pragma unroll
            for (int it = 0; it < 4; ++it) {
                int idx = it * 256 + tid;
                int r = idx >> 4, ch = idx & 15;
                *(short8*)(bn + r * 256 + ((ch * 16) ^ ((r & 7) << 4))) = g[it];
            }
        }
        __syncthreads();
    }

    // 4 sorted kg-runs per query -> 4-way merge -> sorted top-16 packed out
    {
        unsigned* mbuf = (unsigned*)smem;
        int query = wave * 16 + frow;
#pragma unroll
        for (int s = 0; s < 16; ++s) mbuf[query * 65 + kg16 + s] = val[s];
        if (tid < 64) mbuf[tid * 65 + 64] = 0;
        __syncthreads();
        if (tid < 64) {
            unsigned* outp = Cand + (((size_t)nz * 4096 + r0 + tid) * 2 + half) * 16;
            const unsigned* row = mbuf + tid * 65;
            int h0 = 0, h1 = 0, h2 = 0, h3 = 0;
#pragma unroll 1
            for (int kk = 0; kk < 16; ++kk) {
                unsigned c0 = row[h0], c1 = row[16 + h1], c2 = row[32 + h2], c3 = row[48 + h3];
                unsigned mm = max(max(c0, c1), max(c2, c3));
                outp[kk] = mm;
                h0 += (c0 == mm); h1 += (c1 == mm); h2 += (c2 == mm); h3 += (c3 == mm);
            }
        }
    }
}

// ---- 3b. cross-half merge: 2 sorted 16-runs -> final top-16 indices ------
__global__ __launch_bounds__(256) void kmerge_kernel(const unsigned* __restrict__ Cand,
                                                     int* __restrict__ knnr,
                                                     int* __restrict__ knni) {
    int g = blockIdx.x * 256 + threadIdx.x;   // 32768 = nz*4096 + q
    int nz = g >> 12, q = g & 4095;
    int n = nz >> 1;
    int* knn = (nz & 1) ? knni : knnr;
    const unsigned* p = Cand + (size_t)g * 32;
    int* outp = knn + ((size_t)n * 4096 + q) * 16;
    int h0 = 0, h1 = 16;
#pragma unroll
    for (int kk = 0; kk < 16; ++kk) {
        unsigned c0 = p[h0], c1 = p[h1];
        unsigned mm = max(c0, c1);
        outp[kk] = (int)(mm & 0xFFFu);
        h0 += (c0 >= c1); h1 += (c1 > c0);
    }
}

// --- 4. node tables: A1=hr@(W1+W2), A2=hi@W2, B1=hi@(V1+V2), B2=hr@V2 -----
__global__ __launch_bounds__(256) void table_kernel(const float* __restrict__ Pt0r,
                                                    const float* __restrict__ Pt0i,
                                                    const float* __restrict__ Wr,
                                                    const float* __restrict__ Wi,
                                                    float* __restrict__ A1, float* __restrict__ A2,
                                                    float* __restrict__ B1, float* __restrict__ B2) {
    int tbl = blockIdx.y;
    const float* X = (tbl == 0 || tbl == 3) ? Pt0r : Pt0i;
    const float* W = (tbl <= 1) ? Wr : Wi;
    bool comb = (tbl == 0 || tbl == 2);
    float* out = tbl == 0 ? A1 : tbl == 1 ? A2 : tbl == 2 ? B1 : B2;
    __shared__ float Xl[32][128];
    int j0 = blockIdx.x * 32;
    for (int q = threadIdx.x; q < 32 * 128; q += 256)
        Xl[q >> 7][q & 127] = X[(size_t)(j0 + (q >> 7)) * 128 + (q & 127)];
    __syncthreads();
    int c = threadIdx.x & 127;
    int jh = threadIdx.x >> 7;
    float acc[16];
#pragma unroll
    for (int s = 0; s < 16; ++s) acc[s] = 0.f;
    for (int d4 = 0; d4 < 32; ++d4) {
        float w[4];
#pragma unroll
        for (int u = 0; u < 4; ++u) {
            int d = d4 * 4 + u;
            w[u] = W[(size_t)(d + 128) * 128 + c];
            if (comb) w[u] += W[(size_t)d * 128 + c];
        }
#pragma unroll
        for (int jj = 0; jj < 16; ++jj) {
            const float4 xv = *(const float4*)&Xl[jh * 16 + jj][d4 * 4];
            acc[jj] = fmaf(xv.x, w[0], fmaf(xv.y, w[1], fmaf(xv.z, w[2], fmaf(xv.w, w[3], acc[jj]))));
        }
    }
#pragma unroll
    for (int jj = 0; jj < 16; ++jj)
        out[(size_t)(j0 + jh * 16 + jj) * 128 + c] = acc[jj];
}

// ------ 5. pair accumulation: sum leaky(A1[a]-A2[b]+br), float4 lanes -----
__global__ __launch_bounds__(256) void pairsum_kernel(const int* __restrict__ knnr,
                                                      const int* __restrict__ knni,
                                                      const float* __restrict__ A1,
                                                      const float* __restrict__ A2,
                                                      const float* __restrict__ B1,
                                                      const float* __restrict__ B2,
                                                      const float* __restrict__ b_rgb,
                                                      const float* __restrict__ b_ir,
                                                      float* __restrict__ Spart) {
    __shared__ int ia[512], ib[512];
    __shared__ float red[8][256];
    int chunk = blockIdx.x, n = blockIdx.y;
    int i0 = chunk * 32;
    for (int q = threadIdx.x; q < 512; q += 256) {
        int i = i0 + (q >> 4), kk = q & 15;
        ia[q] = knnr[((size_t)n * 4096 + i) * 16 + kk];
        ib[q] = knni[((size_t)n * 4096 + i) * 16 + kk];
    }
    __syncthreads();
    int c4 = threadIdx.x & 31, ph = threadIdx.x >> 5;   // 8 phases
    float4 br = *(const float4*)(b_rgb + c4 * 4);
    float4 bi = *(const float4*)(b_ir + c4 * 4);
    float4 aR = {0.f, 0.f, 0.f, 0.f}, aI = {0.f, 0.f, 0.f, 0.f};
#pragma unroll 8
    for (int q = ph; q < 512; q += 8) {
        int a = ia[q], b = ib[q];
        float4 a1 = *(const float4*)(A1 + (size_t)a * 128 + c4 * 4);
        float4 a2 = *(const float4*)(A2 + (size_t)b * 128 + c4 * 4);
        float4 b1 = *(const float4*)(B1 + (size_t)b * 128 + c4 * 4);
        float4 b2 = *(const float4*)(B2 + (size_t)a * 128 + c4 * 4);
        aR.x += leaky(a1.x - a2.x + br.x); aR.y += leaky(a1.y - a2.y + br.y);
        aR.z += leaky(a1.z - a2.z + br.z); aR.w += leaky(a1.w - a2.w + br.w);
        aI.x += leaky(b1.x - b2.x + bi.x); aI.y += leaky(b1.y - b2.y + bi.y);
        aI.z += leaky(b1.z - b2.z + bi.z); aI.w += leaky(b1.w - b2.w + bi.w);
    }
    *(float4*)&red[ph][c4 * 4] = aR;
    __syncthreads();
    // NOTE: red holds rgb part now; reduce, then reuse for ir
    if (threadIdx.x < 256) {
        // sum phases for rgb columns
    }
    float sR = 0.f;
    {
        int col = threadIdx.x;
        if (col < 128) {
#pragma unroll
            for (int p = 0; p < 8; ++p) sR += red[p][col];
        }
    }
    __syncthreads();
    *(float4*)&red[ph][c4 * 4] = aI;
    __syncthreads();
    float sI = 0.f;
    {
        int col = threadIdx.x;
        if (col < 128) {
#pragma unroll
            for (int p = 0; p < 8; ++p) sI += red[p][col];
        }
    }
    if (threadIdx.x < 128) {
        float* o = Spart + ((size_t)n * 128 + chunk) * 256;
        o[threadIdx.x] = sR;
        o[128 + threadIdx.x] = sI;
    }
}

// ---------- 6a. partial reduce of Spart: 128 partials -> 16 ----------------
__global__ __launch_bounds__(256) void reduce_kernel(const float* __restrict__ Spart,
                                                     float* __restrict__ Spart2) {
    int seg = blockIdx.x, n = blockIdx.y;
    int d = threadIdx.x;
    float s = 0.f;
#pragma unroll
    for (int j = 0; j < 8; ++j)
        s += Spart[((size_t)n * 128 + seg * 8 + j) * 256 + d];
    Spart2[((size_t)n * 16 + seg) * 256 + d] = s;
}

// --------------------- 6b. SE gate (tiny, 1 block/batch) ------------------
__global__ __launch_bounds__(256) void gate_kernel(const float* __restrict__ Spart2,
                                                   const float* __restrict__ se_w1,
                                                   const float* __restrict__ se_b1,
                                                   const float* __restrict__ se_w2,
                                                   const float* __restrict__ se_b2,
                                                   float* __restrict__ gate) {
    int n = blockIdx.x;
    __shared__ float m[256];
    __shared__ float hid[8];
    int d = threadIdx.x;
    float s = 0.f;
#pragma unroll
    for (int seg = 0; seg < 16; ++seg)
        s += Spart2[((size_t)n * 16 + seg) * 256 + d];
    m[d] = s * (1.0f / 65536.0f);
    __syncthreads();
    if (threadIdx.x < 8) {
        float h = se_b1[threadIdx.x];
        for (int dd = 0; dd < 256; ++dd) h += m[dd] * se_w1[dd * 8 + threadIdx.x];
        hid[threadIdx.x] = leaky(h);
    }
    __syncthreads();
    if (threadIdx.x < 128) {
        float z = se_b2[threadIdx.x];
#pragma unroll
        for (int j = 0; j < 8; ++j) z += hid[j] * se_w2[j * 128 + threadIdx.x];
        gate[n * 128 + threadIdx.x] = 1.0f / (1.0f + expf(-z));
    }
}

// -------------------- 7. blend + relu, NCHW output ------------------------
__global__ __launch_bounds__(256) void out_kernel(const float* __restrict__ Pr,
                                                  const float* __restrict__ Pi,
                                                  const float* __restrict__ gate,
                                                  const float* __restrict__ g1p,
                                                  const float* __restrict__ g2p,
                                                  float* __restrict__ out) {
    int q = blockIdx.x * 256 + threadIdx.x;  // float4 idx, 524288 total
    int nc = q >> 10;
    float g = gate[nc];
    float gr = g1p[0] * g, gi = g2p[0] * (1.f - g);
    float4 r = *(const float4*)(Pr + (size_t)q * 4);
    float4 i = *(const float4*)(Pi + (size_t)q * 4);
    float4 o;
    o.x = fmaxf(gr * r.x + gi * i.x, 0.f);
    o.y = fmaxf(gr * r.y + gi * i.y, 0.f);
    o.z = fmaxf(gr * r.z + gi * i.z, 0.f);
    o.w = fmaxf(gr * r.w + gi * i.w, 0.f);
    *(float4*)(out + (size_t)q * 4) = o;
}

extern "C" void kernel_launch(void* const* d_in, const int* in_sizes, int n_in,
                              void* d_out, int out_size, void* d_ws, size_t ws_size,
                              hipStream_t stream) {
    const float* rgb = (const float*)d_in[0];
    const float* ir = (const float*)d_in[1];
    const float* Wr = (const float*)d_in[2];
    const float* br = (const float*)d_in[3];
    const float* Wi = (const float*)d_in[4];
    const float* bi = (const float*)d_in[5];
    const float* sw1 = (const float*)d_in[6];
    const float* sb1 = (const float*)d_in[7];
    const float* sw2 = (const float*)d_in[8];
    const float* sb2 = (const float*)d_in[9];
    const float* g1 = (const float*)d_in[10];
    const float* g2 = (const float*)d_in[11];
    float* out = (float*)d_out;

    char* ws = (char*)d_ws;
    float* Pr = (float*)ws;                     ws += (size_t)8 << 20;
    float* Pi = (float*)ws;                     ws += (size_t)8 << 20;
    unsigned short* xnr = (unsigned short*)ws;  ws += (size_t)4 << 20;
    unsigned short* xni = (unsigned short*)ws;  ws += (size_t)4 << 20;
    float* Pt0r = (float*)ws;                   ws += (size_t)2 << 20;
    float* Pt0i = (float*)ws;                   ws += (size_t)2 << 20;
    int* knnr = (int*)ws;                       ws += (size_t)1 << 20;
    int* knni = (int*)ws;                       ws += (size_t)1 << 20;
    unsigned* Cand = (unsigned*)ws;             ws += (size_t)4 << 20;
    float* A1 = (float*)ws;                     ws += (size_t)2 << 20;
    float* A2 = (float*)ws;                     ws += (size_t)2 << 20;
    float* B1 = (float*)ws;                     ws += (size_t)2 << 20;
    float* B2 = (float*)ws;                     ws += (size_t)2 << 20;
    float* Spart = (float*)ws;                  ws += (size_t)512 << 10;
    float* Spart2 = (float*)ws;                 ws += (size_t)64 << 10;
    float* gate = (float*)ws;                   ws += 4096;

    pool_kernel<<<dim3(2048, 2), 256, 0, stream>>>(rgb, ir, Pr, Pi);
    normT_kernel<<<dim3(128, 4, 2), 256, 0, stream>>>(Pr, Pi, Pt0r, Pt0i, xnr, xni);
    knn_kernel<<<dim3(64, 2, 8), 256, 0, stream>>>(xnr, xni, Cand);
    kmerge_kernel<<<128, 256, 0, stream>>>(Cand, knnr, knni);
    table_kernel<<<dim3(128, 4), 256, 0, stream>>>(Pt0r, Pt0i, Wr, Wi, A1, A2, B1, B2);
    pairsum_kernel<<<dim3(128, 4), 256, 0, stream>>>(knnr, knni, A1, A2, B1, B2, br, bi, Spart);
    reduce_kernel<<<dim3(16, 4), 256, 0, stream>>>(Spart, Spart2);
    gate_kernel<<<4, 256, 0, stream>>>(Spart2, sw1, sb1, sw2, sb2, gate);
    out_kernel<<<2048, 256, 0, stream>>>(Pr, Pi, gate, g1, g2, out);
}